// Round 12
// baseline (162.699 us; speedup 1.0000x reference)
//
#include <hip/hip_runtime.h>
#include <float.h>
#include <math.h>

#define B_SZ   2048
#define D_DIM  256
#define P_DIM  4
#define N_TOT  4096        // 2*B
#define EPS_F  1e-8f
#define RPP    16          // rows per panel
#define NBK    512         // buckets per row histogram
#define BSCALE 128.0f      // bucket width 1/128; tie-approx err ~2.6e-2 << 0.146 (validated)

typedef short  s16x8 __attribute__((ext_vector_type(8)));
typedef float  f32x4 __attribute__((ext_vector_type(4)));

__device__ __forceinline__ unsigned short f2bf(float x) {
    unsigned int b = __float_as_uint(x);
    b += 0x7FFFu + ((b >> 16) & 1u);        // RNE
    return (unsigned short)(b >> 16);
}

// ---------------- Kernel A: row-normalize features -> bf16 ----------------
__global__ __launch_bounds__(64) void normalize_kernel(
    const float* __restrict__ z_i, const float* __restrict__ z_j,
    unsigned short* __restrict__ fb)
{
    int row  = blockIdx.x;
    int lane = threadIdx.x;
    const float* src = (row < B_SZ) ? (z_i + (size_t)row * D_DIM)
                                    : (z_j + (size_t)(row - B_SZ) * D_DIM);
    float4 v = ((const float4*)src)[lane];
    float ss = v.x*v.x + v.y*v.y + v.z*v.z + v.w*v.w;
    #pragma unroll
    for (int off = 32; off > 0; off >>= 1)
        ss += __shfl_down(ss, off, 64);
    ss = __shfl(ss, 0, 64);
    float inv = 1.0f / sqrtf(ss);
    ushort4 o;
    o.x = f2bf(v.x * inv); o.y = f2bf(v.y * inv);
    o.z = f2bf(v.z * inv); o.w = f2bf(v.w * inv);
    ((ushort4*)(fb + (size_t)row * D_DIM))[lane] = o;
}

// ---------------- Kernel B (FUSED, single-pass, pipelined, 16 waves) ----------------
// R11 (8 waves + named-double-buffer pipeline): 160->99us, VGPR 56->84 -- the
// allocator finally granted the pipeline; kernel now latency-bound at 1 block/CU
// (Occupancy 22%, grid 256 = CU count, issue ~15%). Single variable this round:
// 1024-thread blocks -> 16 waves/CU (4/SIMD), 2x TLP at the same grid. Pipeline,
// single-pass count-histogram, plain bank layout (bk&31 fine bits) all unchanged.
// Falsifier: VGPR>=80 but >=85us -> LDS f32-RMW pipe is the wall (aggregate next).
__global__ __launch_bounds__(1024, 4) void panel_kernel(
    const unsigned short* __restrict__ fb,
    const float* __restrict__ physics_i, const float* __restrict__ physics_j,
    float* __restrict__ partial)
{
    __shared__ float    hsum[RPP * NBK];          // 32 KB, plain layout (bank = bk&31)
    __shared__ unsigned hcnt[(RPP / 2) * NBK];    // 16 KB, u16-packed row pairs
    __shared__ float    scr[16];

    int tid = threadIdx.x;
    int L   = tid & 63;
    int w   = tid >> 6;                      // 0..15
    int i0  = blockIdx.x * RPP;

    float4 z4 = {0.f, 0.f, 0.f, 0.f};
    uint4  zu = {0u, 0u, 0u, 0u};
    #pragma unroll
    for (int t = 0; t < 2; ++t) ((float4*)hsum)[tid + t * 1024] = z4;  // 2048 float4
    ((uint4*)hcnt)[tid] = zu;                                          // 1024 uint4

    // A-fragments (proven layout R6-R11): lane holds row i0+(L&15), k-chunk kc at
    // k = kc*32 + (L>>4)*8
    uint4 a4[8];
    #pragma unroll
    for (int kc = 0; kc < 8; ++kc)
        a4[kc] = *(const uint4*)(fb + (size_t)(i0 + (L & 15)) * D_DIM
                                 + kc * 32 + (L >> 4) * 8);
    // labels for this lane's 4 output rows (C row = (L>>4)*4 + q)
    float4 Lr[4];
    #pragma unroll
    for (int q = 0; q < 4; ++q) {
        int r = i0 + (L >> 4) * 4 + q;
        const float* p = (r < B_SZ) ? physics_i + (size_t)r * P_DIM
                                    : physics_j + (size_t)(r - B_SZ) * P_DIM;
        Lr[q] = *(const float4*)p;
    }

    __syncthreads();                         // B0: zeros visible

    #define LOADB(BB, LJ, ct)                                                     \
        {                                                                         \
            int jc_ = (ct) * 256 + w * 16 + (L & 15);                             \
            const unsigned short* bp_ = fb + (size_t)jc_ * D_DIM + (L >> 4) * 8;  \
            _Pragma("unroll")                                                     \
            for (int kc = 0; kc < 8; ++kc)                                        \
                BB[kc] = *(const s16x8*)(bp_ + kc * 32);                          \
            const float* pj_ = (jc_ < B_SZ)                                       \
                ? physics_i + (size_t)jc_ * P_DIM                                 \
                : physics_j + (size_t)(jc_ - B_SZ) * P_DIM;                       \
            LJ = *(const float4*)pj_;                                             \
        }

    #define COMPUTE(BB, LJ, ct)                                                   \
        {                                                                         \
            int jc_ = (ct) * 256 + w * 16 + (L & 15);                             \
            f32x4 acc0 = {0.f, 0.f, 0.f, 0.f};                                    \
            f32x4 acc1 = {0.f, 0.f, 0.f, 0.f};                                    \
            _Pragma("unroll")                                                     \
            for (int kc = 0; kc < 4; ++kc) {                                      \
                acc0 = __builtin_amdgcn_mfma_f32_16x16x32_bf16(                   \
                    __builtin_bit_cast(s16x8, a4[2*kc]),   BB[2*kc],   acc0, 0, 0, 0); \
                acc1 = __builtin_amdgcn_mfma_f32_16x16x32_bf16(                   \
                    __builtin_bit_cast(s16x8, a4[2*kc+1]), BB[2*kc+1], acc1, 0, 0, 0); \
            }                                                                     \
            _Pragma("unroll")                                                     \
            for (int q = 0; q < 4; ++q) {                                         \
                int rq = (L >> 4) * 4 + q;                                        \
                float logit = (acc0[q] + acc1[q]) * 0.5f;  /* /TEMP */            \
                float d = fabsf(Lr[q].x - LJ.x) + fabsf(Lr[q].y - LJ.y)           \
                        + fabsf(Lr[q].z - LJ.z) + fabsf(Lr[q].w - LJ.w);          \
                int bk = (int)(d * BSCALE); if (bk > NBK - 1) bk = NBK - 1;       \
                if (jc_ != i0 + rq) {                                             \
                    atomicAdd(&hsum[rq * NBK + bk], __expf(logit));               \
                    atomicAdd(&hcnt[(rq >> 1) * NBK + bk], 1u << ((rq & 1) * 16));\
                    SL += logit;                                                  \
                }                                                                 \
            }                                                                     \
        }

    // ---- single pass over all 4096 columns: 16 waves x 16 cols = 256 cols/ct,
    //      16 ct-rounds, 2-deep register double-buffer ----
    float SL = 0.f;
    s16x8  bA[8], bB[8];
    float4 LjA, LjB;
    LOADB(bA, LjA, 0)
    for (int ct = 0; ct < 16; ct += 2) {
        LOADB(bB, LjB, ct + 1)               // prefetch next while computing cur
        COMPUTE(bA, LjA, ct)
        if (ct + 2 < 16) LOADB(bA, LjA, ct + 2)
        COMPUTE(bB, LjB, ct + 1)
    }
    __syncthreads();                         // B1: histograms complete

    // ---- wave w owns row w: register suffix-CDF + count-weighted logs ----
    float term = 0.f;
    {
        int row = w;
        const float*    hs = hsum + row * NBK + L * 8;
        const unsigned* hc = hcnt + (row >> 1) * NBK + L * 8;
        int sh = (row & 1) * 16;
        float v[8];
        float fs = 0.f;
        #pragma unroll
        for (int k = 0; k < 8; ++k) { v[k] = hs[k]; fs += v[k]; }
        float s = fs;
        #pragma unroll
        for (int off = 1; off < 64; off <<= 1) {   // inclusive lane-suffix
            float u = __shfl_down(s, off, 64);
            if (L + off < 64) s += u;
        }
        float run = s - fs;                  // strictly-above-lane bucket sum
        #pragma unroll
        for (int k = 7; k >= 0; --k) {
            run += v[k];                     // inclusive suffix = denom of bucket 8L+k
            unsigned c = (hc[k] >> sh) & 0xFFFFu;
            if (c) term += (float)c * __logf(run + EPS_F);
        }
    }

    // ---- block reduce of (SL - term) = sum of pos_log_probs ----
    float acc = SL - term;
    #pragma unroll
    for (int off = 32; off > 0; off >>= 1)
        acc += __shfl_down(acc, off, 64);
    if (L == 0) scr[w] = acc;
    __syncthreads();                         // B2
    if (tid == 0) {
        float s = 0.f;
        #pragma unroll
        for (int w2 = 0; w2 < 16; ++w2) s += scr[w2];
        partial[blockIdx.x] = s;
    }
    #undef LOADB
    #undef COMPUTE
}

// ---------------- Kernel C: final reduce (256 panel partials) ----------------
__global__ __launch_bounds__(256) void final_kernel(
    const float* __restrict__ partial, float* __restrict__ out)
{
    __shared__ float red[4];
    int tid = threadIdx.x;
    float s = 0.f;
    for (int i = tid; i < N_TOT / RPP; i += 256) s += partial[i];
    #pragma unroll
    for (int off = 32; off > 0; off >>= 1)
        s += __shfl_down(s, off, 64);
    if ((tid & 63) == 0) red[tid >> 6] = s;
    __syncthreads();
    if (tid == 0) {
        double tot = (double)red[0] + red[1] + red[2] + red[3];
        out[0] = (float)(-tot / ((double)N_TOT * (N_TOT - 1)));   // loss = -sum/(n(n-1))
    }
}

extern "C" void kernel_launch(void* const* d_in, const int* in_sizes, int n_in,
                              void* d_out, int out_size, void* d_ws, size_t ws_size,
                              hipStream_t stream)
{
    const float* z_i  = (const float*)d_in[0];
    const float* z_j  = (const float*)d_in[1];
    const float* ph_i = (const float*)d_in[2];
    const float* ph_j = (const float*)d_in[3];

    unsigned short* fb      = (unsigned short*)d_ws;                  // 2 MB bf16
    float*          partial = (float*)(fb + (size_t)N_TOT * D_DIM);   // 1 KB

    normalize_kernel<<<N_TOT, 64, 0, stream>>>(z_i, z_j, fb);
    panel_kernel<<<N_TOT / RPP, 1024, 0, stream>>>(fb, ph_i, ph_j, partial);
    final_kernel<<<1, 256, 0, stream>>>(partial, (float*)d_out);
}

// Round 13
// 130.516 us; speedup vs baseline: 1.2466x; 1.2466x over previous
//
#include <hip/hip_runtime.h>
#include <float.h>
#include <math.h>

#define B_SZ   2048
#define D_DIM  256
#define P_DIM  4
#define N_TOT  4096        // 2*B
#define EPS_F  1e-8f
#define RPP    16          // rows per panel
#define NBK    512         // buckets per row histogram
#define BSCALE 128.0f      // bucket width 1/128; tie-approx err ~2.6e-2 << 0.146 (validated)
#define FIXS   1048576.0f  // 2^20 fixed-point scale for exp sums in the u64 cell

typedef short  s16x8 __attribute__((ext_vector_type(8)));
typedef float  f32x4 __attribute__((ext_vector_type(4)));

__device__ __forceinline__ unsigned short f2bf(float x) {
    unsigned int b = __float_as_uint(x);
    b += 0x7FFFu + ((b >> 16) & 1u);        // RNE
    return (unsigned short)(b >> 16);
}

// ---------------- Kernel A: row-normalize features -> bf16 ----------------
__global__ __launch_bounds__(64) void normalize_kernel(
    const float* __restrict__ z_i, const float* __restrict__ z_j,
    unsigned short* __restrict__ fb)
{
    int row  = blockIdx.x;
    int lane = threadIdx.x;
    const float* src = (row < B_SZ) ? (z_i + (size_t)row * D_DIM)
                                    : (z_j + (size_t)(row - B_SZ) * D_DIM);
    float4 v = ((const float4*)src)[lane];
    float ss = v.x*v.x + v.y*v.y + v.z*v.z + v.w*v.w;
    #pragma unroll
    for (int off = 32; off > 0; off >>= 1)
        ss += __shfl_down(ss, off, 64);
    ss = __shfl(ss, 0, 64);
    float inv = 1.0f / sqrtf(ss);
    ushort4 o;
    o.x = f2bf(v.x * inv); o.y = f2bf(v.y * inv);
    o.z = f2bf(v.z * inv); o.w = f2bf(v.w * inv);
    ((ushort4*)(fb + (size_t)row * D_DIM))[lane] = o;
}

// ---------------- Kernel B (FUSED, single-pass, pipelined, u64 atomic) ----------------
// 12-round model fit: the invariant wall is the per-CU LDS-atomic pipe with
// scattered addresses (~7cy/lane-atomic). 2 atomics/pair x 65K pairs/CU ~= 96us,
// matching R6(171,unpipelined), R7(180), R11(99.2, pipelined fire-and-forget),
// R12(103). Fix: fuse (exp,count) -> ONE native u64 ds_add per pair:
//   upd = (1<<40) + u64(exp * 2^20). Low 40b = fixed-point sum (max 2^32.8, no
// carry into count), high bits = count. Halves the lane-atomic stream; fixed-point
// is MORE precise than f32 accumulate. Config = R11 exactly (512thr, VGPR-84
// pipeline, grid 256); single variable.
__global__ __launch_bounds__(512, 2) void panel_kernel(
    const unsigned short* __restrict__ fb,
    const float* __restrict__ physics_i, const float* __restrict__ physics_j,
    float* __restrict__ partial)
{
    __shared__ unsigned long long hist[RPP * NBK];   // 64 KB (sum|count fused)
    __shared__ float scr[8];

    int tid = threadIdx.x;
    int L   = tid & 63;
    int w   = tid >> 6;                      // 0..7
    int i0  = blockIdx.x * RPP;

    uint4 zu = {0u, 0u, 0u, 0u};
    #pragma unroll
    for (int t = 0; t < 8; ++t)              // 4096 uint4 = 64 KB
        ((uint4*)hist)[tid + t * 512] = zu;

    // A-fragments (proven layout R6-R12): lane holds row i0+(L&15), k-chunk kc at
    // k = kc*32 + (L>>4)*8
    uint4 a4[8];
    #pragma unroll
    for (int kc = 0; kc < 8; ++kc)
        a4[kc] = *(const uint4*)(fb + (size_t)(i0 + (L & 15)) * D_DIM
                                 + kc * 32 + (L >> 4) * 8);
    // labels for this lane's 4 output rows (C row = (L>>4)*4 + q)
    float4 Lr[4];
    #pragma unroll
    for (int q = 0; q < 4; ++q) {
        int r = i0 + (L >> 4) * 4 + q;
        const float* p = (r < B_SZ) ? physics_i + (size_t)r * P_DIM
                                    : physics_j + (size_t)(r - B_SZ) * P_DIM;
        Lr[q] = *(const float4*)p;
    }

    __syncthreads();                         // B0: zeros visible

    #define LOADB(BB, LJ, ct)                                                     \
        {                                                                         \
            int jc_ = (ct) * 128 + w * 16 + (L & 15);                             \
            const unsigned short* bp_ = fb + (size_t)jc_ * D_DIM + (L >> 4) * 8;  \
            _Pragma("unroll")                                                     \
            for (int kc = 0; kc < 8; ++kc)                                        \
                BB[kc] = *(const s16x8*)(bp_ + kc * 32);                          \
            const float* pj_ = (jc_ < B_SZ)                                       \
                ? physics_i + (size_t)jc_ * P_DIM                                 \
                : physics_j + (size_t)(jc_ - B_SZ) * P_DIM;                       \
            LJ = *(const float4*)pj_;                                             \
        }

    #define COMPUTE(BB, LJ, ct)                                                   \
        {                                                                         \
            int jc_ = (ct) * 128 + w * 16 + (L & 15);                             \
            f32x4 acc0 = {0.f, 0.f, 0.f, 0.f};                                    \
            f32x4 acc1 = {0.f, 0.f, 0.f, 0.f};                                    \
            _Pragma("unroll")                                                     \
            for (int kc = 0; kc < 4; ++kc) {                                      \
                acc0 = __builtin_amdgcn_mfma_f32_16x16x32_bf16(                   \
                    __builtin_bit_cast(s16x8, a4[2*kc]),   BB[2*kc],   acc0, 0, 0, 0); \
                acc1 = __builtin_amdgcn_mfma_f32_16x16x32_bf16(                   \
                    __builtin_bit_cast(s16x8, a4[2*kc+1]), BB[2*kc+1], acc1, 0, 0, 0); \
            }                                                                     \
            _Pragma("unroll")                                                     \
            for (int q = 0; q < 4; ++q) {                                         \
                int rq = (L >> 4) * 4 + q;                                        \
                float logit = (acc0[q] + acc1[q]) * 0.5f;  /* /TEMP */            \
                float d = fabsf(Lr[q].x - LJ.x) + fabsf(Lr[q].y - LJ.y)           \
                        + fabsf(Lr[q].z - LJ.z) + fabsf(Lr[q].w - LJ.w);          \
                int bk = (int)(d * BSCALE); if (bk > NBK - 1) bk = NBK - 1;       \
                if (jc_ != i0 + rq) {                                             \
                    unsigned long long upd = (1ULL << 40)                         \
                        + (unsigned long long)(__expf(logit) * FIXS);             \
                    atomicAdd(&hist[rq * NBK + bk], upd);                         \
                    SL += logit;                                                  \
                }                                                                 \
            }                                                                     \
        }

    // ---- single pass over all 4096 columns: 8 waves x 16 cols = 128 cols/ct,
    //      32 ct-rounds, 2-deep register double-buffer (R11 schedule) ----
    float SL = 0.f;
    s16x8  bA[8], bB[8];
    float4 LjA, LjB;
    LOADB(bA, LjA, 0)
    for (int ct = 0; ct < 32; ct += 2) {
        LOADB(bB, LjB, ct + 1)               // prefetch next while computing cur
        COMPUTE(bA, LjA, ct)
        if (ct + 2 < 32) LOADB(bA, LjA, ct + 2)
        COMPUTE(bB, LjB, ct + 1)
    }
    __syncthreads();                         // B1: histograms complete

    // ---- wave w owns rows 2w, 2w+1: register suffix-CDF + count-weighted logs ----
    float term = 0.f;
    #pragma unroll
    for (int rr = 0; rr < 2; ++rr) {
        int row = w * 2 + rr;
        const unsigned long long* hr = hist + row * NBK + L * 8;
        float    v[8];
        unsigned c[8];
        float fs = 0.f;
        #pragma unroll
        for (int k = 0; k < 8; ++k) {
            unsigned long long x = hr[k];
            v[k] = (float)(x & 0xFFFFFFFFFFULL) * (1.0f / FIXS);
            c[k] = (unsigned)(x >> 40);
            fs += v[k];
        }
        float s = fs;
        #pragma unroll
        for (int off = 1; off < 64; off <<= 1) {   // inclusive lane-suffix
            float u = __shfl_down(s, off, 64);
            if (L + off < 64) s += u;
        }
        float run = s - fs;                  // strictly-above-lane bucket sum
        #pragma unroll
        for (int k = 7; k >= 0; --k) {
            run += v[k];                     // inclusive suffix = denom of bucket 8L+k
            if (c[k]) term += (float)c[k] * __logf(run + EPS_F);
        }
    }

    // ---- block reduce of (SL - term) = sum of pos_log_probs ----
    float acc = SL - term;
    #pragma unroll
    for (int off = 32; off > 0; off >>= 1)
        acc += __shfl_down(acc, off, 64);
    if (L == 0) scr[w] = acc;
    __syncthreads();                         // B2
    if (tid == 0) {
        float s = 0.f;
        #pragma unroll
        for (int w2 = 0; w2 < 8; ++w2) s += scr[w2];
        partial[blockIdx.x] = s;
    }
    #undef LOADB
    #undef COMPUTE
}

// ---------------- Kernel C: final reduce (256 panel partials) ----------------
__global__ __launch_bounds__(256) void final_kernel(
    const float* __restrict__ partial, float* __restrict__ out)
{
    __shared__ float red[4];
    int tid = threadIdx.x;
    float s = 0.f;
    for (int i = tid; i < N_TOT / RPP; i += 256) s += partial[i];
    #pragma unroll
    for (int off = 32; off > 0; off >>= 1)
        s += __shfl_down(s, off, 64);
    if ((tid & 63) == 0) red[tid >> 6] = s;
    __syncthreads();
    if (tid == 0) {
        double tot = (double)red[0] + red[1] + red[2] + red[3];
        out[0] = (float)(-tot / ((double)N_TOT * (N_TOT - 1)));   // loss = -sum/(n(n-1))
    }
}

extern "C" void kernel_launch(void* const* d_in, const int* in_sizes, int n_in,
                              void* d_out, int out_size, void* d_ws, size_t ws_size,
                              hipStream_t stream)
{
    const float* z_i  = (const float*)d_in[0];
    const float* z_j  = (const float*)d_in[1];
    const float* ph_i = (const float*)d_in[2];
    const float* ph_j = (const float*)d_in[3];

    unsigned short* fb      = (unsigned short*)d_ws;                  // 2 MB bf16
    float*          partial = (float*)(fb + (size_t)N_TOT * D_DIM);   // 1 KB

    normalize_kernel<<<N_TOT, 64, 0, stream>>>(z_i, z_j, fb);
    panel_kernel<<<N_TOT / RPP, 512, 0, stream>>>(fb, ph_i, ph_j, partial);
    final_kernel<<<1, 256, 0, stream>>>(partial, (float*)d_out);
}